// Round 2
// baseline (456.413 us; speedup 1.0000x reference)
//
#include <hip/hip_runtime.h>
#include <hip/hip_bf16.h>

typedef unsigned short u16;
typedef __attribute__((ext_vector_type(8))) short short8;
typedef __attribute__((ext_vector_type(4))) short short4v;
typedef __attribute__((ext_vector_type(4))) float float4v;

__device__ __forceinline__ u16 f2b(float f) {  // RNE f32->bf16 bits (proven)
    unsigned int u = __float_as_uint(f);
    return (u16)((u + 0x7fffu + ((u >> 16) & 1u)) >> 16);
}

#define MFMA(a, b, c) __builtin_amdgcn_mfma_f32_16x16x32_bf16((a), (b), (c), 0, 0, 0)

// ws (u16): wqk[8][128][128] @0 : wqk[h][c][c0] = 0.125 * sum_d Wq[c0][h64+d]*Wk[c][h64+d]
//           wvt[8][64][128] @131072 : Wv_h^T[dv][c]
//           wot[128][512]   @196608 : Wo^T[cout][n]
__global__ void prep_weights(const float* __restrict__ Wq,
                             const float* __restrict__ Wkv,
                             const float* __restrict__ Wo,
                             u16* __restrict__ ws)
{
    const int bid = blockIdx.x, tid = threadIdx.x;
    if (bid < 32) {   // wqk: block = (h, 32-row group g)
        __shared__ float wq_s[128 * 65];
        __shared__ float wk_s[32 * 65];
        const int h = bid >> 2, g = bid & 3;
        for (int i = tid; i < 8192; i += 256) {
            int c0 = i >> 6, d = i & 63;
            wq_s[c0 * 65 + d] = Wq[c0 * 512 + h * 64 + d];
        }
        for (int i = tid; i < 2048; i += 256) {
            int cl = i >> 6, d = i & 63;
            wk_s[cl * 65 + d] = Wkv[(g * 32 + cl) * 1024 + h * 64 + d];
        }
        __syncthreads();
        const int c0 = tid & 127, clb = (tid >> 7) * 16;
        float acc[16];
#pragma unroll
        for (int cc = 0; cc < 16; ++cc) acc[cc] = 0.f;
        for (int d = 0; d < 64; ++d) {
            float a = wq_s[c0 * 65 + d];
#pragma unroll
            for (int cc = 0; cc < 16; ++cc)
                acc[cc] = fmaf(a, wk_s[(clb + cc) * 65 + d], acc[cc]);
        }
#pragma unroll
        for (int cc = 0; cc < 16; ++cc)
            ws[h * 16384 + (g * 32 + clb + cc) * 128 + c0] = f2b(0.125f * acc[cc]);
    } else {
        int idx = (bid - 32) * 256 + tid;
        if (idx < 65536) {                 // wvt
            int h = idx >> 13, c = (idx >> 6) & 127, dv = idx & 63;
            ws[131072 + h * 8192 + dv * 128 + c] =
                f2b(Wkv[c * 1024 + 512 + h * 64 + dv]);
        } else {                           // wot
            int j2 = idx - 65536;
            int cout = j2 >> 9, n = j2 & 511;
            ws[196608 + j2] = f2b(Wo[n * 128 + cout]);
        }
    }
}

// WG = 1024 threads (16 waves), one (b, blk). LDS (u16 el, odd*16B strides):
//   s_x  [208][136] @0      x window [pos][c], rows 196..207 zero
//   t_sw [64][136]  @28288  t = x_int @ Wqk_h
//   v_sw [64][232]  @36992  v^T[dv][j], chunks 26..28 zero
//   p_sw [64][232]  @51840  exp(sim)[i][j], chunks 26..28 zero
//   o_sw [64][72]   @66688  o[i][dv]
//   s_part[3][64] f32 @ byte 142592
//   vmul [224] f32    @ byte 143360 (1.0 where j valid else 0.0)
//   Total 144256 B -> 1 WG/CU.
//
// Structure: x fragments cached in registers across the head loop (s_x is
// static across heads). xa[4][4] = 64 VGPR (fits the 128/wave cap implied by
// 16 waves/WG); only sub==0 waves reload the 5th jt tile from LDS.
// V-wave jt partition == S-wave jt partition so one cache serves both phases.
__global__ __launch_bounds__(1024)
void halo_attn(const float* __restrict__ xg,
               const u16* __restrict__ wqk,
               const u16* __restrict__ wvt,
               const u16* __restrict__ wot,
               const float* __restrict__ bo,
               float* __restrict__ outg)
{
    extern __shared__ u16 lds[];
    u16* s_x  = lds;
    u16* t_sw = lds + 28288;
    u16* v_sw = lds + 36992;
    u16* p_sw = lds + 51840;
    u16* o_sw = lds + 66688;
    float* s_part = (float*)((char*)lds + 142592);
    float* vmul   = (float*)((char*)lds + 143360);

    const int tid  = threadIdx.x;
    const int w    = tid >> 6;
    const int m    = tid & 15;
    const int quad = (tid & 63) >> 4;

    // XCD-swizzle: 128 consecutive logical blocks per XCD (halo L2 reuse)
    const int wg = (blockIdx.x >> 3) + (blockIdx.x & 7) * 128;
    const int b   = wg >> 8;
    const int blk = wg & 255;
    const int by = blk >> 4, bx = blk & 15;
    const int y0 = by * 8 - 3, x0 = bx * 8 - 3;
    const bool inb = (by >= 1) && (by <= 14) && (bx >= 1) && (bx <= 14);

    const short8 zero8 = {0, 0, 0, 0, 0, 0, 0, 0};

    // ---- zero s_x pad rows 196..207 (contiguous 816 dwords) ----
    for (int t = tid; t < 816; t += 1024)
        ((unsigned*)(s_x + 196 * 136))[t] = 0u;
    // ---- zero v/p pad chunks 26..28 (j = 208..231) ----
    for (int t = tid; t < 384; t += 1024) {
        int half = t / 192, u2 = t - half * 192;
        int r = u2 / 3, ch = 26 + (u2 - r * 3);
        u16* base = half ? p_sw : v_sw;
        *(short8*)(base + r * 232 + ch * 8) = zero8;
    }
    // ---- validity mask table ----
    if (tid < 224) {
        int j = tid;
        float v = 0.f;
        if (j < 196) {
            int wy = j / 14, wx = j - wy * 14;
            if (inb || (((unsigned)(y0 + wy) < 128u) && ((unsigned)(x0 + wx) < 128u)))
                v = 1.f;
        }
        vmul[j] = v;
    }
    // ---- stage x window [pos][c] bf16; lanes map to gx for coalescing ----
    for (int idx = tid; idx < 32768; idx += 1024) {
        int wx = idx & 15, wy = (idx >> 4) & 15, c = idx >> 8;
        if (wx < 14 && wy < 14) {
            int gy = y0 + wy, gx = x0 + wx;
            float val = 0.f;
            if (inb || (((unsigned)gy < 128u) && ((unsigned)gx < 128u)))
                val = xg[((b * 128 + c) * 128 + gy) * 128 + gx];
            s_x[(wy * 14 + wx) * 136 + c] = f2b(val);
        }
    }
    __syncthreads();

    // ---- wave roles (fixed for whole kernel) ----
    int nt = 0, sub = 0, startjt = 0, cnt = 0;
    if (w >= 4) {
        int u = w - 4;
        nt = u & 3;              // V: dv-tile;  S: it (same index)
        sub = u >> 2;            // jt group {0-4 | 5-8 | 9-12}
        startjt = sub ? (1 + 4 * sub) : 0;
        cnt = sub ? 4 : 5;
    }

    // ---- preload x fragments into registers (reused for all 8 heads) ----
    short8 xa[4][4];   // 64 VGPR
    if (w < 4) {
        // T waves: interior rows for all 4 i-tiles
#pragma unroll
        for (int it = 0; it < 4; ++it) {
            int i = it * 16 + m;
            int jq = ((i >> 3) + 3) * 14 + (i & 7) + 3;
#pragma unroll
            for (int kk = 0; kk < 4; ++kk)
                xa[it][kk] = *(const short8*)(s_x + jq * 136 + kk * 32 + quad * 8);
        }
    } else {
        // V/S waves: first 4 window-row tiles of this wave's jt group
#pragma unroll
        for (int jj = 0; jj < 4; ++jj) {
            int jt = startjt + jj;
#pragma unroll
            for (int kk = 0; kk < 4; ++kk)
                xa[jj][kk] = *(const short8*)(s_x + (jt * 16 + m) * 136 + kk * 32 + quad * 8);
        }
    }

    float4v res[2];
    res[0] = (float4v){0.f, 0.f, 0.f, 0.f};
    res[1] = (float4v){0.f, 0.f, 0.f, 0.f};

#pragma unroll 1
    for (int h = 0; h < 8; ++h) {
        // ===== Phase T (waves 0..3) + V (waves 4..15) =====
        if (w < 4) {
            short8 bq[2][4];
#pragma unroll
            for (int p2 = 0; p2 < 2; ++p2)
#pragma unroll
                for (int kk = 0; kk < 4; ++kk)
                    bq[p2][kk] = *(const short8*)(wqk + h * 16384 +
                                 ((2 * w + p2) * 16 + m) * 128 + kk * 32 + quad * 8);
#pragma unroll
            for (int it = 0; it < 4; ++it) {
#pragma unroll
                for (int p2 = 0; p2 < 2; ++p2) {
                    float4v c = {0.f, 0.f, 0.f, 0.f};
#pragma unroll
                    for (int kk = 0; kk < 4; ++kk) c = MFMA(xa[it][kk], bq[p2][kk], c);
#pragma unroll
                    for (int r = 0; r < 4; ++r)
                        t_sw[(it * 16 + quad * 4 + r) * 136 + (2 * w + p2) * 16 + m]
                            = f2b(c[r]);
                }
            }
        } else {
            short8 bv[4];
#pragma unroll
            for (int kk = 0; kk < 4; ++kk)
                bv[kk] = *(const short8*)(wvt + h * 8192 + (nt * 16 + m) * 128 +
                                          kk * 32 + quad * 8);
#pragma unroll
            for (int jj = 0; jj < 5; ++jj) if (jj < cnt) {
                int jt = startjt + jj;
                float4v c = {0.f, 0.f, 0.f, 0.f};
#pragma unroll
                for (int kk = 0; kk < 4; ++kk) {
                    short8 a;
                    if (jj < 4) a = xa[jj][kk];
                    else        a = *(const short8*)(s_x + (jt * 16 + m) * 136 +
                                                     kk * 32 + quad * 8);
                    c = MFMA(a, bv[kk], c);
                }
                short4v pk;
#pragma unroll
                for (int r = 0; r < 4; ++r) pk[r] = (short)f2b(c[r]);
                *(short4v*)(v_sw + (nt * 16 + m) * 232 + jt * 16 + quad * 4) = pk;
            }
        }
        __syncthreads();   // barrier 1: t, v ready

        // ===== Phase S (waves 4..15): sim = t @ x_win^T, exp, partial sums =====
        if (w >= 4) {
            const int it = nt;
            short8 ta[4];
#pragma unroll
            for (int kk = 0; kk < 4; ++kk)
                ta[kk] = *(const short8*)(t_sw + (it * 16 + m) * 136 +
                                          kk * 32 + quad * 8);
            float lsum[4] = {0.f, 0.f, 0.f, 0.f};
#pragma unroll
            for (int jj = 0; jj < 5; ++jj) if (jj < cnt) {
                int jt = startjt + jj;
                float4v c = {0.f, 0.f, 0.f, 0.f};
#pragma unroll
                for (int kk = 0; kk < 4; ++kk) {
                    short8 xb;
                    if (jj < 4) xb = xa[jj][kk];
                    else        xb = *(const short8*)(s_x + (jt * 16 + m) * 136 +
                                                      kk * 32 + quad * 8);
                    c = MFMA(ta[kk], xb, c);
                }
                int j = jt * 16 + m;
                float vm = vmul[j];
#pragma unroll
                for (int r = 0; r < 4; ++r) {
                    // masked entries have c==0 exactly (zero x rows): expf(0)*0 = 0
                    float p = __expf(c[r]) * vm;
                    lsum[r] += p;
                    p_sw[(it * 16 + quad * 4 + r) * 232 + j] = f2b(p);
                }
            }
#pragma unroll
            for (int mk = 1; mk < 16; mk <<= 1)
#pragma unroll
                for (int r = 0; r < 4; ++r)
                    lsum[r] += __shfl_xor(lsum[r], mk, 64);
            if (m == 0) {
#pragma unroll
                for (int r = 0; r < 4; ++r)
                    s_part[sub * 64 + it * 16 + quad * 4 + r] = lsum[r];
            }
        }
        __syncthreads();   // barrier 2: p, partial sums ready

        // ===== Phase PV: o = p @ v^T (K=224), normalize -> o_sw =====
        {
            const int it = w & 3, nt2 = w >> 2;
            float4v c = {0.f, 0.f, 0.f, 0.f};
#pragma unroll
            for (int kk = 0; kk < 7; ++kk) {
                short8 pa = *(const short8*)(p_sw + (it * 16 + m) * 232 +
                                             kk * 32 + quad * 8);
                short8 vb = *(const short8*)(v_sw + (nt2 * 16 + m) * 232 +
                                             kk * 32 + quad * 8);
                c = MFMA(pa, vb, c);
            }
#pragma unroll
            for (int r = 0; r < 4; ++r) {
                int i = it * 16 + quad * 4 + r;
                float ss = s_part[i] + s_part[64 + i] + s_part[128 + i];
                o_sw[i * 72 + nt2 * 16 + m] = f2b(c[r] / ss);
            }
        }
        __syncthreads();   // barrier 3: o ready

        // ===== Phase E: res += o @ Wo_h (no barrier after) =====
        {
            const int ct = w & 7, itp = w >> 3;
            short8 bw[2];
#pragma unroll
            for (int kk = 0; kk < 2; ++kk)
                bw[kk] = *(const short8*)(wot + (ct * 16 + m) * 512 + h * 64 +
                                          kk * 32 + quad * 8);
#pragma unroll
            for (int t2 = 0; t2 < 2; ++t2) {
                int it = itp * 2 + t2;
                float4v c = res[t2];
#pragma unroll
                for (int kk = 0; kk < 2; ++kk) {
                    short8 ao = *(const short8*)(o_sw + (it * 16 + m) * 72 +
                                                 kk * 32 + quad * 8);
                    c = MFMA(ao, bw[kk], c);
                }
                res[t2] = c;
            }
        }
    } // heads

    // ---- store fp32 out[b][ch][gy][gx] ----
    {
        const int ct = w & 7, itp = w >> 3;
        const int ch = ct * 16 + m;
        const float bias = bo[ch];
#pragma unroll
        for (int t2 = 0; t2 < 2; ++t2) {
#pragma unroll
            for (int r = 0; r < 4; ++r) {
                int i = (itp * 2 + t2) * 16 + quad * 4 + r;
                int gy = by * 8 + (i >> 3), gx = bx * 8 + (i & 7);
                outg[((b * 128 + ch) * 128 + gy) * 128 + gx] = res[t2][r] + bias;
            }
        }
    }
}

extern "C" void kernel_launch(void* const* d_in, const int* in_sizes, int n_in,
                              void* d_out, int out_size, void* d_ws, size_t ws_size,
                              hipStream_t stream) {
    const float* x   = (const float*)d_in[0];
    const float* Wq  = (const float*)d_in[1];
    const float* Wkv = (const float*)d_in[2];
    const float* Wo  = (const float*)d_in[3];
    const float* bo  = (const float*)d_in[4];
    float* out = (float*)d_out;
    u16* ws = (u16*)d_ws;   // needs 512 KB

    prep_weights<<<dim3(544), dim3(256), 0, stream>>>(Wq, Wkv, Wo, ws);

    (void)hipFuncSetAttribute((const void*)halo_attn,
                              hipFuncAttributeMaxDynamicSharedMemorySize, 144256);
    halo_attn<<<dim3(1024), dim3(1024), 144256, stream>>>(
        x, ws, ws + 131072, ws + 196608, bo, out);
}

// Round 3
// 387.745 us; speedup vs baseline: 1.1771x; 1.1771x over previous
//
#include <hip/hip_runtime.h>
#include <hip/hip_bf16.h>

typedef unsigned short u16;
typedef __attribute__((ext_vector_type(8))) short short8;
typedef __attribute__((ext_vector_type(4))) short short4v;
typedef __attribute__((ext_vector_type(4))) float float4v;

__device__ __forceinline__ u16 f2b(float f) {  // RNE f32->bf16 bits (proven)
    unsigned int u = __float_as_uint(f);
    return (u16)((u + 0x7fffu + ((u >> 16) & 1u)) >> 16);
}

#define MFMA(a, b, c) __builtin_amdgcn_mfma_f32_16x16x32_bf16((a), (b), (c), 0, 0, 0)

// ws (u16): wqk[8][128][128] @0 : wqk[h][c][c0] = 0.125 * sum_d Wq[c0][h64+d]*Wk[c][h64+d]
//           wvt[8][64][128] @131072 : Wv_h^T[dv][c]
//           wot[128][512]   @196608 : Wo^T[cout][n]
__global__ void prep_weights(const float* __restrict__ Wq,
                             const float* __restrict__ Wkv,
                             const float* __restrict__ Wo,
                             u16* __restrict__ ws)
{
    const int bid = blockIdx.x, tid = threadIdx.x;
    if (bid < 32) {   // wqk: block = (h, 32-row group g)
        __shared__ float wq_s[128 * 65];
        __shared__ float wk_s[32 * 65];
        const int h = bid >> 2, g = bid & 3;
        for (int i = tid; i < 8192; i += 256) {
            int c0 = i >> 6, d = i & 63;
            wq_s[c0 * 65 + d] = Wq[c0 * 512 + h * 64 + d];
        }
        for (int i = tid; i < 2048; i += 256) {
            int cl = i >> 6, d = i & 63;
            wk_s[cl * 65 + d] = Wkv[(g * 32 + cl) * 1024 + h * 64 + d];
        }
        __syncthreads();
        const int c0 = tid & 127, clb = (tid >> 7) * 16;
        float acc[16];
#pragma unroll
        for (int cc = 0; cc < 16; ++cc) acc[cc] = 0.f;
        for (int d = 0; d < 64; ++d) {
            float a = wq_s[c0 * 65 + d];
#pragma unroll
            for (int cc = 0; cc < 16; ++cc)
                acc[cc] = fmaf(a, wk_s[(clb + cc) * 65 + d], acc[cc]);
        }
#pragma unroll
        for (int cc = 0; cc < 16; ++cc)
            ws[h * 16384 + (g * 32 + clb + cc) * 128 + c0] = f2b(0.125f * acc[cc]);
    } else {
        int idx = (bid - 32) * 256 + tid;
        if (idx < 65536) {                 // wvt
            int h = idx >> 13, c = (idx >> 6) & 127, dv = idx & 63;
            ws[131072 + h * 8192 + dv * 128 + c] =
                f2b(Wkv[c * 1024 + 512 + h * 64 + dv]);
        } else {                           // wot
            int j2 = idx - 65536;
            int cout = j2 >> 9, n = j2 & 511;
            ws[196608 + j2] = f2b(Wo[n * 128 + cout]);
        }
    }
}

// WG = 1024 threads (16 waves), one (b, blk). LDS (u16 el, odd*16B strides):
//   s_x  [208][136] @0      x window [pos][c], rows 196..207 zero
//   t_sw [64][136]  @28288  t = x_int @ Wqk_h
//   v_sw [64][232]  @36992  v^T[dv][j], chunks 26..28 zero
//   p_sw [64][232]  @51840  exp(sim)[i][j], chunks 26..28 zero
//   o_sw [64][72]   @66688  o[i][dv]
//   s_part[3][64] f32 @ byte 142592
//   vmul [224] f32    @ byte 143360 (1.0 where j valid else 0.0)
//   Total 144256 B -> 1 WG/CU.
//
// x fragments cached in registers across the head loop (s_x static per head).
// __launch_bounds__(1024, 4): 16 waves/WG = 4 waves/EU -> 128-VGPR budget.
// (Plain (1024) made the backend target 8 waves/EU -> 64 VGPRs -> xa spilled
//  to scratch: round-2 showed FETCH 83MB/WRITE 192MB of spill traffic.)
// T-phase loads bq one p2-slice at a time to keep peak live set ~110 VGPRs.
__global__ __launch_bounds__(1024, 4)
void halo_attn(const float* __restrict__ xg,
               const u16* __restrict__ wqk,
               const u16* __restrict__ wvt,
               const u16* __restrict__ wot,
               const float* __restrict__ bo,
               float* __restrict__ outg)
{
    extern __shared__ u16 lds[];
    u16* s_x  = lds;
    u16* t_sw = lds + 28288;
    u16* v_sw = lds + 36992;
    u16* p_sw = lds + 51840;
    u16* o_sw = lds + 66688;
    float* s_part = (float*)((char*)lds + 142592);
    float* vmul   = (float*)((char*)lds + 143360);

    const int tid  = threadIdx.x;
    const int w    = tid >> 6;
    const int m    = tid & 15;
    const int quad = (tid & 63) >> 4;

    // XCD-swizzle: 128 consecutive logical blocks per XCD (halo L2 reuse)
    const int wg = (blockIdx.x >> 3) + (blockIdx.x & 7) * 128;
    const int b   = wg >> 8;
    const int blk = wg & 255;
    const int by = blk >> 4, bx = blk & 15;
    const int y0 = by * 8 - 3, x0 = bx * 8 - 3;
    const bool inb = (by >= 1) && (by <= 14) && (bx >= 1) && (bx <= 14);

    const short8 zero8 = {0, 0, 0, 0, 0, 0, 0, 0};

    // ---- zero s_x pad rows 196..207 (contiguous 816 dwords) ----
    for (int t = tid; t < 816; t += 1024)
        ((unsigned*)(s_x + 196 * 136))[t] = 0u;
    // ---- zero v/p pad chunks 26..28 (j = 208..231) ----
    for (int t = tid; t < 384; t += 1024) {
        int half = t / 192, u2 = t - half * 192;
        int r = u2 / 3, ch = 26 + (u2 - r * 3);
        u16* base = half ? p_sw : v_sw;
        *(short8*)(base + r * 232 + ch * 8) = zero8;
    }
    // ---- validity mask table ----
    if (tid < 224) {
        int j = tid;
        float v = 0.f;
        if (j < 196) {
            int wy = j / 14, wx = j - wy * 14;
            if (inb || (((unsigned)(y0 + wy) < 128u) && ((unsigned)(x0 + wx) < 128u)))
                v = 1.f;
        }
        vmul[j] = v;
    }
    // ---- stage x window [pos][c] bf16; lanes map to gx for coalescing ----
    for (int idx = tid; idx < 32768; idx += 1024) {
        int wx = idx & 15, wy = (idx >> 4) & 15, c = idx >> 8;
        if (wx < 14 && wy < 14) {
            int gy = y0 + wy, gx = x0 + wx;
            float val = 0.f;
            if (inb || (((unsigned)gy < 128u) && ((unsigned)gx < 128u)))
                val = xg[((b * 128 + c) * 128 + gy) * 128 + gx];
            s_x[(wy * 14 + wx) * 136 + c] = f2b(val);
        }
    }
    __syncthreads();

    // ---- wave roles (fixed for whole kernel) ----
    int nt = 0, sub = 0, startjt = 0, cnt = 0;
    if (w >= 4) {
        int u = w - 4;
        nt = u & 3;              // V: dv-tile;  S: it (same index)
        sub = u >> 2;            // jt group {0-4 | 5-8 | 9-12}
        startjt = sub ? (1 + 4 * sub) : 0;
        cnt = sub ? 4 : 5;
    }

    // ---- preload x fragments into registers (reused for all 8 heads) ----
    short8 xa[4][4];   // 64 VGPR
    if (w < 4) {
        // T waves: interior rows for all 4 i-tiles
#pragma unroll
        for (int it = 0; it < 4; ++it) {
            int i = it * 16 + m;
            int jq = ((i >> 3) + 3) * 14 + (i & 7) + 3;
#pragma unroll
            for (int kk = 0; kk < 4; ++kk)
                xa[it][kk] = *(const short8*)(s_x + jq * 136 + kk * 32 + quad * 8);
        }
    } else {
        // V/S waves: first 4 window-row tiles of this wave's jt group
#pragma unroll
        for (int jj = 0; jj < 4; ++jj) {
            int jt = startjt + jj;
#pragma unroll
            for (int kk = 0; kk < 4; ++kk)
                xa[jj][kk] = *(const short8*)(s_x + (jt * 16 + m) * 136 + kk * 32 + quad * 8);
        }
    }

    float4v res[2];
    res[0] = (float4v){0.f, 0.f, 0.f, 0.f};
    res[1] = (float4v){0.f, 0.f, 0.f, 0.f};

#pragma unroll 1
    for (int h = 0; h < 8; ++h) {
        // ===== Phase T (waves 0..3) + V (waves 4..15) =====
        if (w < 4) {
            // p2 outer / it inner: only one bq slice (16 VGPR) live at a time
#pragma unroll
            for (int p2 = 0; p2 < 2; ++p2) {
                short8 bq[4];
#pragma unroll
                for (int kk = 0; kk < 4; ++kk)
                    bq[kk] = *(const short8*)(wqk + h * 16384 +
                                 ((2 * w + p2) * 16 + m) * 128 + kk * 32 + quad * 8);
#pragma unroll
                for (int it = 0; it < 4; ++it) {
                    float4v c = {0.f, 0.f, 0.f, 0.f};
#pragma unroll
                    for (int kk = 0; kk < 4; ++kk) c = MFMA(xa[it][kk], bq[kk], c);
#pragma unroll
                    for (int r = 0; r < 4; ++r)
                        t_sw[(it * 16 + quad * 4 + r) * 136 + (2 * w + p2) * 16 + m]
                            = f2b(c[r]);
                }
            }
        } else {
            short8 bv[4];
#pragma unroll
            for (int kk = 0; kk < 4; ++kk)
                bv[kk] = *(const short8*)(wvt + h * 8192 + (nt * 16 + m) * 128 +
                                          kk * 32 + quad * 8);
#pragma unroll
            for (int jj = 0; jj < 5; ++jj) if (jj < cnt) {
                int jt = startjt + jj;
                float4v c = {0.f, 0.f, 0.f, 0.f};
#pragma unroll
                for (int kk = 0; kk < 4; ++kk) {
                    short8 a;
                    if (jj < 4) a = xa[jj][kk];
                    else        a = *(const short8*)(s_x + (jt * 16 + m) * 136 +
                                                     kk * 32 + quad * 8);
                    c = MFMA(a, bv[kk], c);
                }
                short4v pk;
#pragma unroll
                for (int r = 0; r < 4; ++r) pk[r] = (short)f2b(c[r]);
                *(short4v*)(v_sw + (nt * 16 + m) * 232 + jt * 16 + quad * 4) = pk;
            }
        }
        __syncthreads();   // barrier 1: t, v ready

        // ===== Phase S (waves 4..15): sim = t @ x_win^T, exp, partial sums =====
        if (w >= 4) {
            const int it = nt;
            short8 ta[4];
#pragma unroll
            for (int kk = 0; kk < 4; ++kk)
                ta[kk] = *(const short8*)(t_sw + (it * 16 + m) * 136 +
                                          kk * 32 + quad * 8);
            float lsum[4] = {0.f, 0.f, 0.f, 0.f};
#pragma unroll
            for (int jj = 0; jj < 5; ++jj) if (jj < cnt) {
                int jt = startjt + jj;
                float4v c = {0.f, 0.f, 0.f, 0.f};
#pragma unroll
                for (int kk = 0; kk < 4; ++kk) {
                    short8 xb;
                    if (jj < 4) xb = xa[jj][kk];
                    else        xb = *(const short8*)(s_x + (jt * 16 + m) * 136 +
                                                      kk * 32 + quad * 8);
                    c = MFMA(ta[kk], xb, c);
                }
                int j = jt * 16 + m;
                float vm = vmul[j];
#pragma unroll
                for (int r = 0; r < 4; ++r) {
                    // masked entries have c==0 exactly (zero x rows): expf(0)*0 = 0
                    float p = __expf(c[r]) * vm;
                    lsum[r] += p;
                    p_sw[(it * 16 + quad * 4 + r) * 232 + j] = f2b(p);
                }
            }
#pragma unroll
            for (int mk = 1; mk < 16; mk <<= 1)
#pragma unroll
                for (int r = 0; r < 4; ++r)
                    lsum[r] += __shfl_xor(lsum[r], mk, 64);
            if (m == 0) {
#pragma unroll
                for (int r = 0; r < 4; ++r)
                    s_part[sub * 64 + it * 16 + quad * 4 + r] = lsum[r];
            }
        }
        __syncthreads();   // barrier 2: p, partial sums ready

        // ===== Phase PV: o = p @ v^T (K=224), normalize -> o_sw =====
        {
            const int it = w & 3, nt2 = w >> 2;
            float4v c = {0.f, 0.f, 0.f, 0.f};
#pragma unroll
            for (int kk = 0; kk < 7; ++kk) {
                short8 pa = *(const short8*)(p_sw + (it * 16 + m) * 232 +
                                             kk * 32 + quad * 8);
                short8 vb = *(const short8*)(v_sw + (nt2 * 16 + m) * 232 +
                                             kk * 32 + quad * 8);
                c = MFMA(pa, vb, c);
            }
#pragma unroll
            for (int r = 0; r < 4; ++r) {
                int i = it * 16 + quad * 4 + r;
                float ss = s_part[i] + s_part[64 + i] + s_part[128 + i];
                o_sw[i * 72 + nt2 * 16 + m] = f2b(c[r] / ss);
            }
        }
        __syncthreads();   // barrier 3: o ready

        // ===== Phase E: res += o @ Wo_h (no barrier after) =====
        {
            const int ct = w & 7, itp = w >> 3;
            short8 bw[2];
#pragma unroll
            for (int kk = 0; kk < 2; ++kk)
                bw[kk] = *(const short8*)(wot + (ct * 16 + m) * 512 + h * 64 +
                                          kk * 32 + quad * 8);
#pragma unroll
            for (int t2 = 0; t2 < 2; ++t2) {
                int it = itp * 2 + t2;
                float4v c = res[t2];
#pragma unroll
                for (int kk = 0; kk < 2; ++kk) {
                    short8 ao = *(const short8*)(o_sw + (it * 16 + m) * 72 +
                                                 kk * 32 + quad * 8);
                    c = MFMA(ao, bw[kk], c);
                }
                res[t2] = c;
            }
        }
    } // heads

    // ---- store fp32 out[b][ch][gy][gx] ----
    {
        const int ct = w & 7, itp = w >> 3;
        const int ch = ct * 16 + m;
        const float bias = bo[ch];
#pragma unroll
        for (int t2 = 0; t2 < 2; ++t2) {
#pragma unroll
            for (int r = 0; r < 4; ++r) {
                int i = (itp * 2 + t2) * 16 + quad * 4 + r;
                int gy = by * 8 + (i >> 3), gx = bx * 8 + (i & 7);
                outg[((b * 128 + ch) * 128 + gy) * 128 + gx] = res[t2][r] + bias;
            }
        }
    }
}

extern "C" void kernel_launch(void* const* d_in, const int* in_sizes, int n_in,
                              void* d_out, int out_size, void* d_ws, size_t ws_size,
                              hipStream_t stream) {
    const float* x   = (const float*)d_in[0];
    const float* Wq  = (const float*)d_in[1];
    const float* Wkv = (const float*)d_in[2];
    const float* Wo  = (const float*)d_in[3];
    const float* bo  = (const float*)d_in[4];
    float* out = (float*)d_out;
    u16* ws = (u16*)d_ws;   // needs 512 KB

    prep_weights<<<dim3(544), dim3(256), 0, stream>>>(Wq, Wkv, Wo, ws);

    (void)hipFuncSetAttribute((const void*)halo_attn,
                              hipFuncAttributeMaxDynamicSharedMemorySize, 144256);
    halo_attn<<<dim3(1024), dim3(1024), 144256, stream>>>(
        x, ws, ws + 131072, ws + 196608, bo, out);
}

// Round 4
// 379.363 us; speedup vs baseline: 1.2031x; 1.0221x over previous
//
#include <hip/hip_runtime.h>
#include <hip/hip_bf16.h>

typedef unsigned short u16;
typedef __attribute__((ext_vector_type(8))) short short8;
typedef __attribute__((ext_vector_type(4))) short short4v;
typedef __attribute__((ext_vector_type(4))) float float4v;

__device__ __forceinline__ u16 f2b(float f) {  // RNE f32->bf16 bits (proven)
    unsigned int u = __float_as_uint(f);
    return (u16)((u + 0x7fffu + ((u >> 16) & 1u)) >> 16);
}

#define MFMA(a, b, c) __builtin_amdgcn_mfma_f32_16x16x32_bf16((a), (b), (c), 0, 0, 0)

// ws (u16): wqk[8][128][128] @0 : wqk[h][c][c0] = 0.125 * sum_d Wq[c0][h64+d]*Wk[c][h64+d]
//           wvt[8][64][128] @131072 : Wv_h^T[dv][c]
//           wot[128][512]   @196608 : Wo^T[cout][n]
__global__ void prep_weights(const float* __restrict__ Wq,
                             const float* __restrict__ Wkv,
                             const float* __restrict__ Wo,
                             u16* __restrict__ ws)
{
    const int bid = blockIdx.x, tid = threadIdx.x;
    if (bid < 32) {   // wqk: block = (h, 32-row group g)
        __shared__ float wq_s[128 * 65];
        __shared__ float wk_s[32 * 65];
        const int h = bid >> 2, g = bid & 3;
        for (int i = tid; i < 8192; i += 256) {
            int c0 = i >> 6, d = i & 63;
            wq_s[c0 * 65 + d] = Wq[c0 * 512 + h * 64 + d];
        }
        for (int i = tid; i < 2048; i += 256) {
            int cl = i >> 6, d = i & 63;
            wk_s[cl * 65 + d] = Wkv[(g * 32 + cl) * 1024 + h * 64 + d];
        }
        __syncthreads();
        const int c0 = tid & 127, clb = (tid >> 7) * 16;
        float acc[16];
#pragma unroll
        for (int cc = 0; cc < 16; ++cc) acc[cc] = 0.f;
        for (int d = 0; d < 64; ++d) {
            float a = wq_s[c0 * 65 + d];
#pragma unroll
            for (int cc = 0; cc < 16; ++cc)
                acc[cc] = fmaf(a, wk_s[(clb + cc) * 65 + d], acc[cc]);
        }
#pragma unroll
        for (int cc = 0; cc < 16; ++cc)
            ws[h * 16384 + (g * 32 + clb + cc) * 128 + c0] = f2b(0.125f * acc[cc]);
    } else {
        int idx = (bid - 32) * 256 + tid;
        if (idx < 65536) {                 // wvt
            int h = idx >> 13, c = (idx >> 6) & 127, dv = idx & 63;
            ws[131072 + h * 8192 + dv * 128 + c] =
                f2b(Wkv[c * 1024 + 512 + h * 64 + dv]);
        } else {                           // wot
            int j2 = idx - 65536;
            int cout = j2 >> 9, n = j2 & 511;
            ws[196608 + j2] = f2b(Wo[n * 128 + cout]);
        }
    }
}

// WG = 1024 threads (16 waves), one (b, blk). LDS (u16 el, odd*16B strides):
//   s_x  [208][136] @0      x window [pos][c], rows 196..207 zero
//   t_sw [64][136]  @28288  t = x_int @ Wqk_h
//   v_sw [64][232]  @36992  v^T[dv][j], chunks 26..28 zero
//   p_sw [64][232]  @51840  exp(sim)[i][j], chunks 26..28 zero
//   o_sw [64][72]   @66688  o[i][dv]
//   s_part[3][64] f32 @ byte 142592
//   vmul [224] f32    @ byte 143360 (1.0 where j valid else 0.0)
//   Total 144256 B -> 1 WG/CU.
//
// Register budget: amdgpu_waves_per_eu(4,4) pins BOTH ends of the occupancy
// range at 4 waves/EU -> 128-VGPR budget. (launch_bounds' min-only form left
// the allocator targeting 8/EU = 64 regs and spilling: rounds 2/3 showed
// 76-160 MiB of scratch write traffic at VGPR_Count=64.)
// xa cache shrunk to [3][4] = 48 regs so peak live set ~100 < 128 with margin;
// 4th/5th x tiles are re-read from LDS per phase.
__global__
__attribute__((amdgpu_flat_work_group_size(1024, 1024), amdgpu_waves_per_eu(4, 4)))
void halo_attn(const float* __restrict__ xg,
               const u16* __restrict__ wqk,
               const u16* __restrict__ wvt,
               const u16* __restrict__ wot,
               const float* __restrict__ bo,
               float* __restrict__ outg)
{
    extern __shared__ u16 lds[];
    u16* s_x  = lds;
    u16* t_sw = lds + 28288;
    u16* v_sw = lds + 36992;
    u16* p_sw = lds + 51840;
    u16* o_sw = lds + 66688;
    float* s_part = (float*)((char*)lds + 142592);
    float* vmul   = (float*)((char*)lds + 143360);

    const int tid  = threadIdx.x;
    const int w    = tid >> 6;
    const int m    = tid & 15;
    const int quad = (tid & 63) >> 4;

    // XCD-swizzle: 128 consecutive logical blocks per XCD (halo L2 reuse)
    const int wg = (blockIdx.x >> 3) + (blockIdx.x & 7) * 128;
    const int b   = wg >> 8;
    const int blk = wg & 255;
    const int by = blk >> 4, bx = blk & 15;
    const int y0 = by * 8 - 3, x0 = bx * 8 - 3;
    const bool inb = (by >= 1) && (by <= 14) && (bx >= 1) && (bx <= 14);

    const short8 zero8 = {0, 0, 0, 0, 0, 0, 0, 0};

    // ---- zero s_x pad rows 196..207 (contiguous 816 dwords) ----
    for (int t = tid; t < 816; t += 1024)
        ((unsigned*)(s_x + 196 * 136))[t] = 0u;
    // ---- zero v/p pad chunks 26..28 (j = 208..231) ----
    for (int t = tid; t < 384; t += 1024) {
        int half = t / 192, u2 = t - half * 192;
        int r = u2 / 3, ch = 26 + (u2 - r * 3);
        u16* base = half ? p_sw : v_sw;
        *(short8*)(base + r * 232 + ch * 8) = zero8;
    }
    // ---- validity mask table ----
    if (tid < 224) {
        int j = tid;
        float v = 0.f;
        if (j < 196) {
            int wy = j / 14, wx = j - wy * 14;
            if (inb || (((unsigned)(y0 + wy) < 128u) && ((unsigned)(x0 + wx) < 128u)))
                v = 1.f;
        }
        vmul[j] = v;
    }
    // ---- stage x window [pos][c] bf16; lanes map to gx for coalescing ----
    for (int idx = tid; idx < 32768; idx += 1024) {
        int wx = idx & 15, wy = (idx >> 4) & 15, c = idx >> 8;
        if (wx < 14 && wy < 14) {
            int gy = y0 + wy, gx = x0 + wx;
            float val = 0.f;
            if (inb || (((unsigned)gy < 128u) && ((unsigned)gx < 128u)))
                val = xg[((b * 128 + c) * 128 + gy) * 128 + gx];
            s_x[(wy * 14 + wx) * 136 + c] = f2b(val);
        }
    }
    __syncthreads();

    // ---- wave roles (fixed for whole kernel) ----
    int nt = 0, sub = 0, startjt = 0, cnt = 0;
    if (w >= 4) {
        int u = w - 4;
        nt = u & 3;              // V: dv-tile;  S: it (same index)
        sub = u >> 2;            // jt group {0-4 | 5-8 | 9-12}
        startjt = sub ? (1 + 4 * sub) : 0;
        cnt = sub ? 4 : 5;
    }

    // ---- preload x fragments into registers (reused for all 8 heads) ----
    short8 xa[3][4];   // 48 VGPR
    if (w < 4) {
        // T waves: interior rows for i-tiles 0..2 (tile 3 re-read from LDS)
#pragma unroll
        for (int it = 0; it < 3; ++it) {
            int i = it * 16 + m;
            int jq = ((i >> 3) + 3) * 14 + (i & 7) + 3;
#pragma unroll
            for (int kk = 0; kk < 4; ++kk)
                xa[it][kk] = *(const short8*)(s_x + jq * 136 + kk * 32 + quad * 8);
        }
    } else {
        // V/S waves: first 3 window-row tiles of this wave's jt group
#pragma unroll
        for (int jj = 0; jj < 3; ++jj) {
            int jt = startjt + jj;
#pragma unroll
            for (int kk = 0; kk < 4; ++kk)
                xa[jj][kk] = *(const short8*)(s_x + (jt * 16 + m) * 136 + kk * 32 + quad * 8);
        }
    }

    float4v res[2];
    res[0] = (float4v){0.f, 0.f, 0.f, 0.f};
    res[1] = (float4v){0.f, 0.f, 0.f, 0.f};

#pragma unroll 1
    for (int h = 0; h < 8; ++h) {
        // ===== Phase T (waves 0..3) + V (waves 4..15) =====
        if (w < 4) {
            // p2 outer / it inner: only one bq slice (16 VGPR) live at a time
#pragma unroll
            for (int p2 = 0; p2 < 2; ++p2) {
                short8 bq[4];
#pragma unroll
                for (int kk = 0; kk < 4; ++kk)
                    bq[kk] = *(const short8*)(wqk + h * 16384 +
                                 ((2 * w + p2) * 16 + m) * 128 + kk * 32 + quad * 8);
#pragma unroll
                for (int it = 0; it < 4; ++it) {
                    int i = it * 16 + m;
                    int jq = ((i >> 3) + 3) * 14 + (i & 7) + 3;
                    float4v c = {0.f, 0.f, 0.f, 0.f};
#pragma unroll
                    for (int kk = 0; kk < 4; ++kk) {
                        short8 a;
                        if (it < 3) a = xa[it][kk];
                        else        a = *(const short8*)(s_x + jq * 136 +
                                                         kk * 32 + quad * 8);
                        c = MFMA(a, bq[kk], c);
                    }
#pragma unroll
                    for (int r = 0; r < 4; ++r)
                        t_sw[(it * 16 + quad * 4 + r) * 136 + (2 * w + p2) * 16 + m]
                            = f2b(c[r]);
                }
            }
        } else {
            short8 bv[4];
#pragma unroll
            for (int kk = 0; kk < 4; ++kk)
                bv[kk] = *(const short8*)(wvt + h * 8192 + (nt * 16 + m) * 128 +
                                          kk * 32 + quad * 8);
#pragma unroll
            for (int jj = 0; jj < 5; ++jj) if (jj < cnt) {
                int jt = startjt + jj;
                float4v c = {0.f, 0.f, 0.f, 0.f};
#pragma unroll
                for (int kk = 0; kk < 4; ++kk) {
                    short8 a;
                    if (jj < 3) a = xa[jj][kk];
                    else        a = *(const short8*)(s_x + (jt * 16 + m) * 136 +
                                                     kk * 32 + quad * 8);
                    c = MFMA(a, bv[kk], c);
                }
                short4v pk;
#pragma unroll
                for (int r = 0; r < 4; ++r) pk[r] = (short)f2b(c[r]);
                *(short4v*)(v_sw + (nt * 16 + m) * 232 + jt * 16 + quad * 4) = pk;
            }
        }
        __syncthreads();   // barrier 1: t, v ready

        // ===== Phase S (waves 4..15): sim = t @ x_win^T, exp, partial sums =====
        if (w >= 4) {
            const int it = nt;
            short8 ta[4];
#pragma unroll
            for (int kk = 0; kk < 4; ++kk)
                ta[kk] = *(const short8*)(t_sw + (it * 16 + m) * 136 +
                                          kk * 32 + quad * 8);
            float lsum[4] = {0.f, 0.f, 0.f, 0.f};
#pragma unroll
            for (int jj = 0; jj < 5; ++jj) if (jj < cnt) {
                int jt = startjt + jj;
                float4v c = {0.f, 0.f, 0.f, 0.f};
#pragma unroll
                for (int kk = 0; kk < 4; ++kk) {
                    short8 xb;
                    if (jj < 3) xb = xa[jj][kk];
                    else        xb = *(const short8*)(s_x + (jt * 16 + m) * 136 +
                                                      kk * 32 + quad * 8);
                    c = MFMA(ta[kk], xb, c);
                }
                int j = jt * 16 + m;
                float vm = vmul[j];
#pragma unroll
                for (int r = 0; r < 4; ++r) {
                    // masked entries have c==0 exactly (zero x rows): expf(0)*0 = 0
                    float p = __expf(c[r]) * vm;
                    lsum[r] += p;
                    p_sw[(it * 16 + quad * 4 + r) * 232 + j] = f2b(p);
                }
            }
#pragma unroll
            for (int mk = 1; mk < 16; mk <<= 1)
#pragma unroll
                for (int r = 0; r < 4; ++r)
                    lsum[r] += __shfl_xor(lsum[r], mk, 64);
            if (m == 0) {
#pragma unroll
                for (int r = 0; r < 4; ++r)
                    s_part[sub * 64 + it * 16 + quad * 4 + r] = lsum[r];
            }
        }
        __syncthreads();   // barrier 2: p, partial sums ready

        // ===== Phase PV: o = p @ v^T (K=224), normalize -> o_sw =====
        {
            const int it = w & 3, nt2 = w >> 2;
            float4v c = {0.f, 0.f, 0.f, 0.f};
#pragma unroll
            for (int kk = 0; kk < 7; ++kk) {
                short8 pa = *(const short8*)(p_sw + (it * 16 + m) * 232 +
                                             kk * 32 + quad * 8);
                short8 vb = *(const short8*)(v_sw + (nt2 * 16 + m) * 232 +
                                             kk * 32 + quad * 8);
                c = MFMA(pa, vb, c);
            }
#pragma unroll
            for (int r = 0; r < 4; ++r) {
                int i = it * 16 + quad * 4 + r;
                float ss = s_part[i] + s_part[64 + i] + s_part[128 + i];
                o_sw[i * 72 + nt2 * 16 + m] = f2b(c[r] / ss);
            }
        }
        __syncthreads();   // barrier 3: o ready

        // ===== Phase E: res += o @ Wo_h (no barrier after) =====
        {
            const int ct = w & 7, itp = w >> 3;
            short8 bw[2];
#pragma unroll
            for (int kk = 0; kk < 2; ++kk)
                bw[kk] = *(const short8*)(wot + (ct * 16 + m) * 512 + h * 64 +
                                          kk * 32 + quad * 8);
#pragma unroll
            for (int t2 = 0; t2 < 2; ++t2) {
                int it = itp * 2 + t2;
                float4v c = res[t2];
#pragma unroll
                for (int kk = 0; kk < 2; ++kk) {
                    short8 ao = *(const short8*)(o_sw + (it * 16 + m) * 72 +
                                                 kk * 32 + quad * 8);
                    c = MFMA(ao, bw[kk], c);
                }
                res[t2] = c;
            }
        }
    } // heads

    // ---- store fp32 out[b][ch][gy][gx] ----
    {
        const int ct = w & 7, itp = w >> 3;
        const int ch = ct * 16 + m;
        const float bias = bo[ch];
#pragma unroll
        for (int t2 = 0; t2 < 2; ++t2) {
#pragma unroll
            for (int r = 0; r < 4; ++r) {
                int i = (itp * 2 + t2) * 16 + quad * 4 + r;
                int gy = by * 8 + (i >> 3), gx = bx * 8 + (i & 7);
                outg[((b * 128 + ch) * 128 + gy) * 128 + gx] = res[t2][r] + bias;
            }
        }
    }
}

extern "C" void kernel_launch(void* const* d_in, const int* in_sizes, int n_in,
                              void* d_out, int out_size, void* d_ws, size_t ws_size,
                              hipStream_t stream) {
    const float* x   = (const float*)d_in[0];
    const float* Wq  = (const float*)d_in[1];
    const float* Wkv = (const float*)d_in[2];
    const float* Wo  = (const float*)d_in[3];
    const float* bo  = (const float*)d_in[4];
    float* out = (float*)d_out;
    u16* ws = (u16*)d_ws;   // needs 512 KB

    prep_weights<<<dim3(544), dim3(256), 0, stream>>>(Wq, Wkv, Wo, ws);

    (void)hipFuncSetAttribute((const void*)halo_attn,
                              hipFuncAttributeMaxDynamicSharedMemorySize, 144256);
    halo_attn<<<dim3(1024), dim3(1024), 144256, stream>>>(
        x, ws, ws + 131072, ws + 196608, bo, out);
}